// Round 2
// 401.515 us; speedup vs baseline: 1.0223x; 1.0223x over previous
//
#include <hip/hip_runtime.h>

// Correlation cost volume: out[b,d,h,w] = mean_c( x[b,c,h,w] * y[b,c,h,w-d] ), 0 for w<d
// B=8, C=32, H=256, W=512, D=48
//
// R4 (= R3 design, de-risked launch bounds after infra failure):
//  - x dropped from LDS (L1/L2 serve the 3-wave re-read within a block)
//  - y staged with global_load_lds (async DMA, no ds_writes, no staging VGPRs)
//  - NT=192, DP=8 -> acc[8][4]=32 regs; __launch_bounds__(192,6): VGPR<=85
//    (no spill risk), occupancy cap 24 waves/CU (was 16). LDS 11.0 KB/block.

constexpr int kB = 8;
constexpr int kC = 32;
constexpr int kH = 256;
constexpr int kW = 512;
constexpr int kD = 48;

constexpr int WT = 128;          // w-tile per block
constexpr int YW = kD + WT;      // 176 floats of y per staged row
constexpr int NT = 192;          // 3 waves
constexpr int CH = 16;           // channels per staging phase
constexpr int DP = 8;            // d per thread (6 d-groups)
constexpr int WP = 4;            // w per thread (32 w-chunks)
constexpr int NCHUNK = CH * YW * 4 / 1024;   // 11 x 1024B LDS chunks per phase

__device__ __forceinline__ void load_lds16(const float* g, float* l) {
    // HW writes lane i at (wave-uniform lds base) + i*16; gptr is per-lane.
    __builtin_amdgcn_global_load_lds(
        (const __attribute__((address_space(1))) void*)g,
        (__attribute__((address_space(3))) void*)l, 16, 0, 0);
}

__global__ __launch_bounds__(NT, 6) void corr_kernel(
    const float* __restrict__ x, const float* __restrict__ y, float* __restrict__ out)
{
    __shared__ __align__(16) float ys[CH * YW];   // 11264 B, linear for global_load_lds

    const int tid = threadIdx.x;
    const int w0  = blockIdx.x * WT;
    const int h   = blockIdx.y;
    const int b   = blockIdx.z;

    const size_t cs = (size_t)kH * kW;

    const int lw    = tid & 31;          // 32 w-chunks of 4
    const int dgrp  = tid >> 5;          // 6 d-groups of 8
    const int wi    = lw << 2;           // 0..124
    const int d0    = dgrp * DP;         // 0,8,...,40 (4-aligned -> static yv idx)
    const int ybase = wi + 40 - d0;      // 4-aligned, in [0,164]; yv[1..11] used

    const int wv = tid >> 6;             // wave 0..2
    const int ln = tid & 63;

    const float* xbh = x + ((size_t)b * kC * kH + h) * kW + w0 + wi;  // per-lane x base
    const float* ybh = y + ((size_t)b * kC * kH + h) * kW;            // row base (c=0)

    float acc[DP][WP];
    #pragma unroll
    for (int dd = 0; dd < DP; ++dd)
        #pragma unroll
        for (int j = 0; j < WP; ++j) acc[dd][j] = 0.f;

    for (int p = 0; p < 2; ++p) {
        if (p) __syncthreads();          // WAR: finish compute before restage

        // stage y[p*16..p*16+15][w0-48 .. w0+127] -> ys, 1024B per wave-instr.
        // chunk k covers floats [256k, 256k+256); lane ln supplies float 256k+4*ln.
        for (int k = wv; k < NCHUNK; k += 3) {
            const int f   = (k << 8) + (ln << 2);
            const int r   = f / YW;                  // channel row 0..15
            const int col = f - r * YW;              // 0..175 (multiple of 4)
            int wcol = w0 - kD + col;
            if (wcol < 0) wcol = 0;                  // left edge: clamp, zero-fixed below
            load_lds16(ybh + (size_t)(p * CH + r) * cs + wcol, &ys[k << 8]);
        }
        __syncthreads();                 // barrier drains vmcnt -> loads landed

        if (w0 == 0) {                   // exact zeros for w<0 columns (block-uniform)
            for (int idx = tid; idx < CH * kD; idx += NT) {
                const int r = idx / kD;
                ys[r * YW + (idx - r * kD)] = 0.f;
            }
            __syncthreads();
        }

        // compute: per c, 1 global x-load (L1/L2-resident, 512B/wave-half) +
        // 3 lane-contiguous ds_read_b128 + 32 FMAs.
        #pragma unroll 2
        for (int c = 0; c < CH; ++c) {
            const float4 x4 = *(const float4*)(xbh + (size_t)(p * CH + c) * cs);
            const float* yc = &ys[c * YW + ybase];
            const float4 y0 = *(const float4*)(yc);
            const float4 y1 = *(const float4*)(yc + 4);
            const float4 y2 = *(const float4*)(yc + 8);
            const float xv[4]  = {x4.x, x4.y, x4.z, x4.w};
            const float yv[12] = {y0.x, y0.y, y0.z, y0.w, y1.x, y1.y, y1.z, y1.w,
                                  y2.x, y2.y, y2.z, y2.w};
            // out[d=d0+dd][w=w0+wi+j] needs ys col wi+j-(d0+dd)+48 -> yv[8+j-dd]
            #pragma unroll
            for (int dd = 0; dd < DP; ++dd)
                #pragma unroll
                for (int j = 0; j < WP; ++j)
                    acc[dd][j] += xv[j] * yv[8 + j - dd];
        }
    }

    // epilogue: scale 1/32, coalesced float4 stores (512B per wave-half per dd)
    const float scale = 1.0f / kC;
    #pragma unroll
    for (int dd = 0; dd < DP; ++dd) {
        float* o = out + (((size_t)b * kD + d0 + dd) * kH + h) * kW + w0 + wi;
        *(float4*)o = make_float4(acc[dd][0] * scale, acc[dd][1] * scale,
                                  acc[dd][2] * scale, acc[dd][3] * scale);
    }
}

extern "C" void kernel_launch(void* const* d_in, const int* in_sizes, int n_in,
                              void* d_out, int out_size, void* d_ws, size_t ws_size,
                              hipStream_t stream) {
    const float* x = (const float*)d_in[0];
    const float* y = (const float*)d_in[1];
    float* out = (float*)d_out;

    dim3 grid(kW / WT, kH, kB);   // (4, 256, 8) = 8192 blocks
    corr_kernel<<<grid, NT, 0, stream>>>(x, y, out);
}